// Round 11
// baseline (379.316 us; speedup 1.0000x reference)
//
#include <hip/hip_runtime.h>
#include <math.h>

// B=64, S=64, H_DIM=768, N_HEADS=12, D=64. All I/O f32.
// 4 kernels. ws bytes: qkvb u16[9437184] @0 ; Zh u16[3145728] @18874368 ;
//           part f32[16][64][4096] @25165824
// d_out f32: y [262144] then masked_scores [3145728].
// Masked positions: ref=-inf -> finite NEG_BIG (never materialize inf:
// finite-math folds ==-INFINITY; expf(NEG_BIG-m)==0).
// All GEMMs plain bf16 MFMA, f32 accum.
// mfma_f32_16x16x32_bf16: A row=ln&15,k=(ln>>4)*8+j; B col=ln&15;
// C/D col=ln&15,row=(ln>>4)*4+reg.
// Z frag order: z_flat[b][k] at ((rt*1536+kf)*64+lz)*8+j, rt=b>>4, kf=k>>5,
// lz=((k>>3)&3)*16+(b&15), j=k&7 -> contiguous 1KB wave reads.
// k_lin v6: register-staged W (one contiguous >=512B segment per load instr;
// r6/r10 lesson: multi-segment scatter caps TA issue rate ~3TB/s), Z direct
// from global (coalesced, L1-dedup), zero barriers, 16 waves/CU.

#define NEG_BIG (-1.0e30f)

typedef __attribute__((ext_vector_type(8))) short bf16x8;
typedef __attribute__((ext_vector_type(4))) float f32x4;

static __device__ __forceinline__ unsigned short f2bf(float x) {
    unsigned u = __builtin_bit_cast(unsigned, x);
    return (unsigned short)((u + 0x7FFFu + ((u >> 16) & 1u)) >> 16);   // RNE
}
static __device__ __forceinline__ ushort4 f2bf4(float4 v) {
    ushort4 r; r.x = f2bf(v.x); r.y = f2bf(v.y); r.z = f2bf(v.z); r.w = f2bf(v.w); return r;
}

// ---------------- Kernel 1: QKV GEMM, plain bf16 MFMA ----------------
__global__ __launch_bounds__(256, 4) void k_qkv(const float* __restrict__ X,
                                                const float* __restrict__ Wp,
                                                unsigned short* __restrict__ qkvb) {
    __shared__ unsigned short Ah[128][72];
    __shared__ unsigned short Bh[128][72];
    const int t  = threadIdx.x;
    const int wv = t >> 6, ln = t & 63;
    const int lr = ln & 15;
    const int kq = (ln >> 4) * 8;
    const int rbase = (ln >> 4) * 4;
    const int m0 = (blockIdx.x / 18) * 128;
    const int j0 = (blockIdx.x % 18) * 128;
    const f32x4 zero4 = {0.f, 0.f, 0.f, 0.f};

    f32x4 acc[2][8];
#pragma unroll
    for (int rt = 0; rt < 2; ++rt)
#pragma unroll
        for (int ct = 0; ct < 8; ++ct) acc[rt][ct] = zero4;

    for (int k0 = 0; k0 < 768; k0 += 64) {
#pragma unroll
        for (int i = 0; i < 8; ++i) {
            const int q   = t + 256 * i;
            const int row = q >> 4;
            const int kc  = (q & 15) * 4;
            float4 xa = *reinterpret_cast<const float4*>(&X[(size_t)(m0 + row) * 768 + k0 + kc]);
            *reinterpret_cast<ushort4*>(&Ah[row][kc]) = f2bf4(xa);
            float4 wb = *reinterpret_cast<const float4*>(&Wp[(size_t)(j0 + row) * 768 + k0 + kc]);
            *reinterpret_cast<ushort4*>(&Bh[row][kc]) = f2bf4(wb);
        }
        __syncthreads();
#pragma unroll
        for (int ks = 0; ks < 2; ++ks) {
            const int kb = ks * 32 + kq;
            bf16x8 a0 = *reinterpret_cast<const bf16x8*>(&Ah[wv * 32 + lr][kb]);
            bf16x8 a1 = *reinterpret_cast<const bf16x8*>(&Ah[wv * 32 + 16 + lr][kb]);
#pragma unroll
            for (int ct = 0; ct < 8; ++ct) {
                bf16x8 bh = *reinterpret_cast<const bf16x8*>(&Bh[ct * 16 + lr][kb]);
                acc[0][ct] = __builtin_amdgcn_mfma_f32_16x16x32_bf16(a0, bh, acc[0][ct], 0, 0, 0);
                acc[1][ct] = __builtin_amdgcn_mfma_f32_16x16x32_bf16(a1, bh, acc[1][ct], 0, 0, 0);
            }
        }
        __syncthreads();
    }
#pragma unroll
    for (int rt = 0; rt < 2; ++rt)
#pragma unroll
        for (int ct = 0; ct < 8; ++ct)
#pragma unroll
            for (int r = 0; r < 4; ++r) {
                const int m = m0 + wv * 32 + rt * 16 + rbase + r;
                const int j = j0 + ct * 16 + lr;
                const int b = m >> 6, s = m & 63;
                const int n = j / 192, f = j % 192;
                qkvb[(((size_t)b * 12 + n) * 64 + s) * 192 + f] = f2bf(acc[rt][ct][r]);
            }
}

// ---------------- Kernel 2: attention per (b,n), plain bf16 MFMA ----------------
__global__ __launch_bounds__(256, 4) void k_attn(const unsigned short* __restrict__ qkvb,
                                                 float* __restrict__ msk,
                                                 unsigned short* __restrict__ Zh) {
    __shared__ unsigned short Qh[64][72];
    __shared__ unsigned short Kh[64][72];
    __shared__ unsigned short Vth[64][72];   // V transposed [d][s]
    __shared__ unsigned short Ph[64][72];
    const int t  = threadIdx.x;
    const int wv = t >> 6, ln = t & 63;
    const int lr = ln & 15;
    const int kq = (ln >> 4) * 8;
    const int rbase = (ln >> 4) * 4;
    const int bn = blockIdx.x;
    const int bb = bn / 12, nn = bn % 12;
    const unsigned short* base = qkvb + (size_t)bn * 12288;
    const f32x4 zero4 = {0.f, 0.f, 0.f, 0.f};

#pragma unroll
    for (int i = 0; i < 6; ++i) {
        const int q   = t + 256 * i;       // 1536 ushort8 granules
        const int row = q / 24;
        const int c8  = (q % 24) * 8;
        const int sec = c8 >> 6;
        const int d0  = c8 & 63;
        bf16x8 v = *reinterpret_cast<const bf16x8*>(&base[(size_t)row * 192 + c8]);
        if (sec == 0) {
            *reinterpret_cast<bf16x8*>(&Qh[row][d0]) = v;
        } else if (sec == 1) {
            *reinterpret_cast<bf16x8*>(&Kh[row][d0]) = v;
        } else {
#pragma unroll
            for (int jj = 0; jj < 8; ++jj) Vth[d0 + jj][row] = (unsigned short)v[jj];
        }
    }
    __syncthreads();

    f32x4 acc[4];
#pragma unroll
    for (int ct = 0; ct < 4; ++ct) acc[ct] = zero4;
#pragma unroll
    for (int ks = 0; ks < 2; ++ks) {
        const int kb = ks * 32 + kq;
        bf16x8 qh = *reinterpret_cast<const bf16x8*>(&Qh[wv * 16 + lr][kb]);
#pragma unroll
        for (int ct = 0; ct < 4; ++ct) {
            bf16x8 kh = *reinterpret_cast<const bf16x8*>(&Kh[ct * 16 + lr][kb]);
            acc[ct] = __builtin_amdgcn_mfma_f32_16x16x32_bf16(qh, kh, acc[ct], 0, 0, 0);
        }
    }

    float s_[4][4];
#pragma unroll
    for (int ct = 0; ct < 4; ++ct)
#pragma unroll
        for (int r = 0; r < 4; ++r) {
            const int row = wv * 16 + rbase + r;
            const int col = ct * 16 + lr;
            float s = (col > row) ? NEG_BIG : acc[ct][r] * 0.125f;
            s_[ct][r] = s;
            msk[(size_t)bn * 4096 + (size_t)row * 64 + col] = s;
        }
    float m[4], sum[4], p[4][4];
#pragma unroll
    for (int r = 0; r < 4; ++r)
        m[r] = fmaxf(fmaxf(s_[0][r], s_[1][r]), fmaxf(s_[2][r], s_[3][r]));
#pragma unroll
    for (int off = 1; off <= 8; off <<= 1)
#pragma unroll
        for (int r = 0; r < 4; ++r) m[r] = fmaxf(m[r], __shfl_xor(m[r], off));
#pragma unroll
    for (int r = 0; r < 4; ++r) sum[r] = 0.f;
#pragma unroll
    for (int ct = 0; ct < 4; ++ct)
#pragma unroll
        for (int r = 0; r < 4; ++r) { p[ct][r] = expf(s_[ct][r] - m[r]); sum[r] += p[ct][r]; }
#pragma unroll
    for (int off = 1; off <= 8; off <<= 1)
#pragma unroll
        for (int r = 0; r < 4; ++r) sum[r] += __shfl_xor(sum[r], off);
#pragma unroll
    for (int ct = 0; ct < 4; ++ct)
#pragma unroll
        for (int r = 0; r < 4; ++r)
            Ph[wv * 16 + rbase + r][ct * 16 + lr] = f2bf(p[ct][r] * (1.f / sum[r]));
    // wave-local LDS dependency only

    f32x4 o_[4];
#pragma unroll
    for (int ct = 0; ct < 4; ++ct) o_[ct] = zero4;
#pragma unroll
    for (int ks = 0; ks < 2; ++ks) {
        const int kb = ks * 32 + kq;
        bf16x8 ph = *reinterpret_cast<const bf16x8*>(&Ph[wv * 16 + lr][kb]);
#pragma unroll
        for (int ct = 0; ct < 4; ++ct) {
            bf16x8 vh = *reinterpret_cast<const bf16x8*>(&Vth[ct * 16 + lr][kb]);
            o_[ct] = __builtin_amdgcn_mfma_f32_16x16x32_bf16(ph, vh, o_[ct], 0, 0, 0);
        }
    }
    const int rt_z = bb >> 4;
#pragma unroll
    for (int ct = 0; ct < 4; ++ct)
#pragma unroll
        for (int r = 0; r < 4; ++r) {
            const int srow = wv * 16 + rbase + r;
            const int d    = ct * 16 + lr;
            const int k    = nn * 4096 + srow * 64 + d;
            const int lz   = (((k >> 3) & 3) << 4) + (bb & 15);
            const size_t zi = (((size_t)rt_z * 1536 + (k >> 5)) * 64 + lz) * 8 + (k & 7);
            Zh[zi] = f2bf(o_[ct][r]);
        }
}

// ---------------- Kernel 3: output projection v6 ----------------
// part[ksp][b][o] = sum_k Z[b][k] W[o][k]; grid 1024 = 16 ksp x 64 units.
// Wave owns 16 o-cols. Super-step BK=128: 8 contiguous-segment W loads to
// REGISTERS (issued one full compute-phase early), convert->padded LDS;
// Z read directly from global (frag-order coalesced 1KB). No barriers.
__global__ __launch_bounds__(256, 4) void k_lin(const unsigned short* __restrict__ Zh,
                                                const float* __restrict__ Wl,
                                                float* __restrict__ part) {
    __shared__ unsigned short Wbuf[4][16][136];   // per-wave 16 rows x 128 bf16, +8 pad (272B rows)
    const int t  = threadIdx.x;
    const int wv = t >> 6, ln = t & 63;
    const int lr = ln & 15;
    const int rbase = (ln >> 4) * 4;
    const int ksp  = blockIdx.x >> 6;          // 0..15
    const int unit = blockIdx.x & 63;          // 0..63
    const int o0   = unit * 64;
    const f32x4 zero4 = {0.f, 0.f, 0.f, 0.f};

    // W addressing: load i covers rows 2i (lanes 0-31) / 2i+1 (lanes 32-63),
    // each lane 16B at (ln&31)*16 within the row's 512B super-step slice.
    const int rlo = (ln >= 32) ? 1 : 0;
    const float* wbase = Wl + (size_t)(o0 + wv * 16) * 49152 + ksp * 3072 + (ln & 31) * 4;
    char* wrow = (char*)&Wbuf[wv][0][0];

    f32x4 acc[4];
#pragma unroll
    for (int rt = 0; rt < 4; ++rt) acc[rt] = zero4;

    float4 wreg[8];
#define WLOAD(ss_)                                                                  \
    {                                                                               \
        _Pragma("unroll")                                                           \
        for (int i = 0; i < 8; ++i)                                                 \
            wreg[i] = *reinterpret_cast<const float4*>(                             \
                wbase + (size_t)(2 * i + rlo) * 49152 + (ss_) * 128);               \
    }
#define WWRITE()                                                                    \
    {                                                                               \
        _Pragma("unroll")                                                           \
        for (int i = 0; i < 8; ++i) {                                               \
            unsigned u0 = (unsigned)f2bf(wreg[i].x) | ((unsigned)f2bf(wreg[i].y) << 16); \
            unsigned u1 = (unsigned)f2bf(wreg[i].z) | ((unsigned)f2bf(wreg[i].w) << 16); \
            uint2 pk; pk.x = u0; pk.y = u1;                                         \
            *reinterpret_cast<uint2*>(wrow + (2 * i + rlo) * 272 + (ln & 31) * 8) = pk; \
        }                                                                           \
    }

    WLOAD(0)
    WWRITE()
    for (int ss = 0; ss < 24; ++ss) {
        if (ss + 1 < 24) WLOAD(ss + 1)     // in flight across this super-step's compute
#pragma unroll
        for (int st = 0; st < 2; ++st) {
            const int ts = ss * 2 + st;
            const int kf0 = ksp * 96 + ts * 2;
            bf16x8 z[8];
#pragma unroll
            for (int q = 0; q < 8; ++q) {
                const int ks_ = q & 1, rt_ = q >> 1;
                z[q] = *reinterpret_cast<const bf16x8*>(
                    Zh + (size_t)rt_ * 786432 + ((size_t)(kf0 + ks_) * 64 + ln) * 8);
            }
#pragma unroll
            for (int ks_ = 0; ks_ < 2; ++ks_) {
                const int slot = st * 2 + ks_;
                bf16x8 wf = *reinterpret_cast<const bf16x8*>(
                    wrow + lr * 272 + slot * 64 + (ln >> 4) * 16);
#pragma unroll
                for (int rt = 0; rt < 4; ++rt)
                    acc[rt] = __builtin_amdgcn_mfma_f32_16x16x32_bf16(
                        z[rt * 2 + ks_], wf, acc[rt], 0, 0, 0);
            }
        }
        if (ss + 1 < 24) {
            asm volatile("s_waitcnt lgkmcnt(0)" ::: "memory");   // my frag reads done
            __builtin_amdgcn_sched_barrier(0);
            WWRITE()
        }
    }
#undef WLOAD
#undef WWRITE

    const int ocol = o0 + wv * 16 + lr;
#pragma unroll
    for (int rt = 0; rt < 4; ++rt)
#pragma unroll
        for (int r = 0; r < 4; ++r)
            part[((size_t)ksp * 64 + rt * 16 + rbase + r) * 4096 + ocol] = acc[rt][r];
}

// ---------------- Kernel 4: reduce 16 split-K partials + bias ----------------
__global__ __launch_bounds__(256) void k_reduce(const float* __restrict__ part,
                                                const float* __restrict__ bias,
                                                float* __restrict__ y) {
    const int idx = blockIdx.x * 256 + threadIdx.x;
    const int o = idx & 4095;
    const int b = idx >> 12;
    float s = bias[o];
#pragma unroll
    for (int ksp = 0; ksp < 16; ++ksp)
        s += part[((size_t)ksp * 64 + b) * 4096 + o];
    y[idx] = s;
}

extern "C" void kernel_launch(void* const* d_in, const int* in_sizes, int n_in,
                              void* d_out, int out_size, void* d_ws, size_t ws_size,
                              hipStream_t stream) {
    const float* x  = (const float*)d_in[0];
    const float* Wp = (const float*)d_in[1];
    const float* Wl = (const float*)d_in[2];
    const float* bl = (const float*)d_in[3];
    float* out = (float*)d_out;

    unsigned short* qkvb = (unsigned short*)d_ws;                       // 9437184 u16
    unsigned short* Zh   = (unsigned short*)((char*)d_ws + 18874368);   // 3145728 u16
    float*          part = (float*)((char*)d_ws + 25165824);            // 16x64x4096 f32
    float* y    = out;
    float* msk  = out + 262144;

    hipLaunchKernelGGL(k_qkv,    dim3(576),  dim3(256), 0, stream, x, Wp, qkvb);
    hipLaunchKernelGGL(k_attn,   dim3(768),  dim3(256), 0, stream, qkvb, msk, Zh);
    hipLaunchKernelGGL(k_lin,    dim3(1024), dim3(256), 0, stream, Zh, Wl, part);
    hipLaunchKernelGGL(k_reduce, dim3(1024), dim3(256), 0, stream, part, bl, y);
}

// Round 12
// 299.416 us; speedup vs baseline: 1.2669x; 1.2669x over previous
//
#include <hip/hip_runtime.h>
#include <math.h>

// B=64, S=64, H_DIM=768, N_HEADS=12, D=64. All I/O f32.
// 4 kernels. ws bytes: qkvb u16[9437184] @0 ; Zh u16[3145728] @18874368 ;
//           part f32[16][64][4096] @25165824
// d_out f32: y [262144] then masked_scores [3145728].
// Masked positions: ref=-inf -> finite NEG_BIG (never materialize inf:
// finite-math folds ==-INFINITY; expf(NEG_BIG-m)==0).
// All GEMMs plain bf16 MFMA, f32 accum.
// mfma_f32_16x16x32_bf16: A row=ln&15,k=(ln>>4)*8+j; B col=ln&15;
// C/D col=ln&15,row=(ln>>4)*4+reg.
// Z frag order: z_flat[b][k] at ((rt*1536+kf)*64+lz)*8+j, rt=b>>4, kf=k>>5,
// lz=((k>>3)&3)*16+(b&15), j=k&7 -> contiguous 1KB wave reads/stages.
// k_lin v7 (fixes r11's vmcnt inversion: in-order vmcnt retirement meant any
// wait on current-step Z loads forced next-step W loads to complete, exposing
// full HBM latency every step): Z consumed ONLY via LDS (lgkm domain, staged
// by gload_lds one sub ahead); W reg-loaded one sub ahead (2-segment 512B
// instrs), waited with counted vmcnt(4) AFTER ~3K cycles of pure-LDS compute.

#define NEG_BIG (-1.0e30f)

typedef __attribute__((ext_vector_type(8))) short bf16x8;
typedef __attribute__((ext_vector_type(4))) float f32x4;
typedef const __attribute__((address_space(1))) void gvoid_t;
typedef __attribute__((address_space(3))) void svoid_t;

static __device__ __forceinline__ unsigned short f2bf(float x) {
    unsigned u = __builtin_bit_cast(unsigned, x);
    return (unsigned short)((u + 0x7FFFu + ((u >> 16) & 1u)) >> 16);   // RNE
}
static __device__ __forceinline__ ushort4 f2bf4(float4 v) {
    ushort4 r; r.x = f2bf(v.x); r.y = f2bf(v.y); r.z = f2bf(v.z); r.w = f2bf(v.w); return r;
}

// ---------------- Kernel 1: QKV GEMM, plain bf16 MFMA ----------------
__global__ __launch_bounds__(256, 4) void k_qkv(const float* __restrict__ X,
                                                const float* __restrict__ Wp,
                                                unsigned short* __restrict__ qkvb) {
    __shared__ unsigned short Ah[128][72];
    __shared__ unsigned short Bh[128][72];
    const int t  = threadIdx.x;
    const int wv = t >> 6, ln = t & 63;
    const int lr = ln & 15;
    const int kq = (ln >> 4) * 8;
    const int rbase = (ln >> 4) * 4;
    const int m0 = (blockIdx.x / 18) * 128;
    const int j0 = (blockIdx.x % 18) * 128;
    const f32x4 zero4 = {0.f, 0.f, 0.f, 0.f};

    f32x4 acc[2][8];
#pragma unroll
    for (int rt = 0; rt < 2; ++rt)
#pragma unroll
        for (int ct = 0; ct < 8; ++ct) acc[rt][ct] = zero4;

    for (int k0 = 0; k0 < 768; k0 += 64) {
#pragma unroll
        for (int i = 0; i < 8; ++i) {
            const int q   = t + 256 * i;
            const int row = q >> 4;
            const int kc  = (q & 15) * 4;
            float4 xa = *reinterpret_cast<const float4*>(&X[(size_t)(m0 + row) * 768 + k0 + kc]);
            *reinterpret_cast<ushort4*>(&Ah[row][kc]) = f2bf4(xa);
            float4 wb = *reinterpret_cast<const float4*>(&Wp[(size_t)(j0 + row) * 768 + k0 + kc]);
            *reinterpret_cast<ushort4*>(&Bh[row][kc]) = f2bf4(wb);
        }
        __syncthreads();
#pragma unroll
        for (int ks = 0; ks < 2; ++ks) {
            const int kb = ks * 32 + kq;
            bf16x8 a0 = *reinterpret_cast<const bf16x8*>(&Ah[wv * 32 + lr][kb]);
            bf16x8 a1 = *reinterpret_cast<const bf16x8*>(&Ah[wv * 32 + 16 + lr][kb]);
#pragma unroll
            for (int ct = 0; ct < 8; ++ct) {
                bf16x8 bh = *reinterpret_cast<const bf16x8*>(&Bh[ct * 16 + lr][kb]);
                acc[0][ct] = __builtin_amdgcn_mfma_f32_16x16x32_bf16(a0, bh, acc[0][ct], 0, 0, 0);
                acc[1][ct] = __builtin_amdgcn_mfma_f32_16x16x32_bf16(a1, bh, acc[1][ct], 0, 0, 0);
            }
        }
        __syncthreads();
    }
#pragma unroll
    for (int rt = 0; rt < 2; ++rt)
#pragma unroll
        for (int ct = 0; ct < 8; ++ct)
#pragma unroll
            for (int r = 0; r < 4; ++r) {
                const int m = m0 + wv * 32 + rt * 16 + rbase + r;
                const int j = j0 + ct * 16 + lr;
                const int b = m >> 6, s = m & 63;
                const int n = j / 192, f = j % 192;
                qkvb[(((size_t)b * 12 + n) * 64 + s) * 192 + f] = f2bf(acc[rt][ct][r]);
            }
}

// ---------------- Kernel 2: attention per (b,n), plain bf16 MFMA ----------------
__global__ __launch_bounds__(256, 4) void k_attn(const unsigned short* __restrict__ qkvb,
                                                 float* __restrict__ msk,
                                                 unsigned short* __restrict__ Zh) {
    __shared__ unsigned short Qh[64][72];
    __shared__ unsigned short Kh[64][72];
    __shared__ unsigned short Vth[64][72];   // V transposed [d][s]
    __shared__ unsigned short Ph[64][72];
    const int t  = threadIdx.x;
    const int wv = t >> 6, ln = t & 63;
    const int lr = ln & 15;
    const int kq = (ln >> 4) * 8;
    const int rbase = (ln >> 4) * 4;
    const int bn = blockIdx.x;
    const int bb = bn / 12, nn = bn % 12;
    const unsigned short* base = qkvb + (size_t)bn * 12288;
    const f32x4 zero4 = {0.f, 0.f, 0.f, 0.f};

#pragma unroll
    for (int i = 0; i < 6; ++i) {
        const int q   = t + 256 * i;
        const int row = q / 24;
        const int c8  = (q % 24) * 8;
        const int sec = c8 >> 6;
        const int d0  = c8 & 63;
        bf16x8 v = *reinterpret_cast<const bf16x8*>(&base[(size_t)row * 192 + c8]);
        if (sec == 0) {
            *reinterpret_cast<bf16x8*>(&Qh[row][d0]) = v;
        } else if (sec == 1) {
            *reinterpret_cast<bf16x8*>(&Kh[row][d0]) = v;
        } else {
#pragma unroll
            for (int jj = 0; jj < 8; ++jj) Vth[d0 + jj][row] = (unsigned short)v[jj];
        }
    }
    __syncthreads();

    f32x4 acc[4];
#pragma unroll
    for (int ct = 0; ct < 4; ++ct) acc[ct] = zero4;
#pragma unroll
    for (int ks = 0; ks < 2; ++ks) {
        const int kb = ks * 32 + kq;
        bf16x8 qh = *reinterpret_cast<const bf16x8*>(&Qh[wv * 16 + lr][kb]);
#pragma unroll
        for (int ct = 0; ct < 4; ++ct) {
            bf16x8 kh = *reinterpret_cast<const bf16x8*>(&Kh[ct * 16 + lr][kb]);
            acc[ct] = __builtin_amdgcn_mfma_f32_16x16x32_bf16(qh, kh, acc[ct], 0, 0, 0);
        }
    }

    float s_[4][4];
#pragma unroll
    for (int ct = 0; ct < 4; ++ct)
#pragma unroll
        for (int r = 0; r < 4; ++r) {
            const int row = wv * 16 + rbase + r;
            const int col = ct * 16 + lr;
            float s = (col > row) ? NEG_BIG : acc[ct][r] * 0.125f;
            s_[ct][r] = s;
            msk[(size_t)bn * 4096 + (size_t)row * 64 + col] = s;
        }
    float m[4], sum[4], p[4][4];
#pragma unroll
    for (int r = 0; r < 4; ++r)
        m[r] = fmaxf(fmaxf(s_[0][r], s_[1][r]), fmaxf(s_[2][r], s_[3][r]));
#pragma unroll
    for (int off = 1; off <= 8; off <<= 1)
#pragma unroll
        for (int r = 0; r < 4; ++r) m[r] = fmaxf(m[r], __shfl_xor(m[r], off));
#pragma unroll
    for (int r = 0; r < 4; ++r) sum[r] = 0.f;
#pragma unroll
    for (int ct = 0; ct < 4; ++ct)
#pragma unroll
        for (int r = 0; r < 4; ++r) { p[ct][r] = expf(s_[ct][r] - m[r]); sum[r] += p[ct][r]; }
#pragma unroll
    for (int off = 1; off <= 8; off <<= 1)
#pragma unroll
        for (int r = 0; r < 4; ++r) sum[r] += __shfl_xor(sum[r], off);
#pragma unroll
    for (int ct = 0; ct < 4; ++ct)
#pragma unroll
        for (int r = 0; r < 4; ++r)
            Ph[wv * 16 + rbase + r][ct * 16 + lr] = f2bf(p[ct][r] * (1.f / sum[r]));
    // wave-local LDS dependency only

    f32x4 o_[4];
#pragma unroll
    for (int ct = 0; ct < 4; ++ct) o_[ct] = zero4;
#pragma unroll
    for (int ks = 0; ks < 2; ++ks) {
        const int kb = ks * 32 + kq;
        bf16x8 ph = *reinterpret_cast<const bf16x8*>(&Ph[wv * 16 + lr][kb]);
#pragma unroll
        for (int ct = 0; ct < 4; ++ct) {
            bf16x8 vh = *reinterpret_cast<const bf16x8*>(&Vth[ct * 16 + lr][kb]);
            o_[ct] = __builtin_amdgcn_mfma_f32_16x16x32_bf16(ph, vh, o_[ct], 0, 0, 0);
        }
    }
    const int rt_z = bb >> 4;
#pragma unroll
    for (int ct = 0; ct < 4; ++ct)
#pragma unroll
        for (int r = 0; r < 4; ++r) {
            const int srow = wv * 16 + rbase + r;
            const int d    = ct * 16 + lr;
            const int k    = nn * 4096 + srow * 64 + d;
            const int lz   = (((k >> 3) & 3) << 4) + (bb & 15);
            const size_t zi = (((size_t)rt_z * 1536 + (k >> 5)) * 64 + lz) * 8 + (k & 7);
            Zh[zi] = f2bf(o_[ct][r]);
        }
}

// ---------------- Kernel 3: output projection v7 ----------------
// part[ksp][b][o] = sum_k Z[b][k] W[o][k]; grid 1024 = 16 ksp x 64 units
// (64 o-cols each). Sub-step BK=128, 24 subs. Compute phase touches ONLY LDS.
__global__ __launch_bounds__(256, 2) void k_lin(const unsigned short* __restrict__ Zh,
                                                const float* __restrict__ Wl,
                                                float* __restrict__ part) {
    __shared__ __align__(16) unsigned short Zlds[2][16][64][8];   // 32 KB [buf][rt*4+kfo][lane][8]
    __shared__ __align__(16) unsigned short Wbuf[4][2][16][136];  // 34.8 KB padded rows (272B)
    const int t  = threadIdx.x;
    const int wv = t >> 6, ln = t & 63;
    const int lr = ln & 15;
    const int rbase = (ln >> 4) * 4;
    const int ksp  = blockIdx.x >> 6;          // 0..15
    const int unit = blockIdx.x & 63;          // 0..63
    const int o0   = unit * 64;
    const f32x4 zero4 = {0.f, 0.f, 0.f, 0.f};

    // W: load i covers rows 2i (lanes 0-31) / 2i+1 (lanes 32-63); lane 16B at
    // (ln&31)*16 within the row's 512B sub-slice -> 2 contiguous 512B segments.
    const int rlo = (ln >= 32) ? 1 : 0;
    const float* wbase = Wl + (size_t)(o0 + wv * 16) * 49152 + ksp * 3072 + (ln & 31) * 4;
    char* wrow = (char*)&Wbuf[wv][0][0][0];

    f32x4 acc[4];
#pragma unroll
    for (int rt = 0; rt < 4; ++rt) acc[rt] = zero4;

    float4 wreg[8];
#define WLOAD(sub_)                                                                 \
    {                                                                               \
        _Pragma("unroll")                                                           \
        for (int i = 0; i < 8; ++i)                                                 \
            wreg[i] = *reinterpret_cast<const float4*>(                             \
                wbase + (size_t)(2 * i + rlo) * 49152 + (sub_) * 128);              \
    }
#define WWRITE(buf_)                                                                \
    {                                                                               \
        _Pragma("unroll")                                                           \
        for (int i = 0; i < 8; ++i) {                                               \
            unsigned u0 = (unsigned)f2bf(wreg[i].x) | ((unsigned)f2bf(wreg[i].y) << 16); \
            unsigned u1 = (unsigned)f2bf(wreg[i].z) | ((unsigned)f2bf(wreg[i].w) << 16); \
            uint2 pk; pk.x = u0; pk.y = u1;                                         \
            *reinterpret_cast<uint2*>(wrow + ((buf_) * 16 + 2 * i + rlo) * 272 + (ln & 31) * 8) = pk; \
        }                                                                           \
    }
    // Z stage: wave wv stages rt=wv, kfo=0..3 (4 x 1KB contiguous gload_lds)
#define ZSTAGE(buf_, sub_)                                                          \
    {                                                                               \
        const int kf0 = ksp * 96 + (sub_) * 4;                                      \
        _Pragma("unroll")                                                           \
        for (int q = 0; q < 4; ++q) {                                               \
            const unsigned short* src = Zh +                                        \
                ((size_t)(wv * 1536 + kf0 + q) * 64 + ln) * 8;                      \
            __builtin_amdgcn_global_load_lds((gvoid_t*)src,                         \
                (svoid_t*)&Zlds[buf_][wv * 4 + q][0][0], 16, 0, 0);                 \
        }                                                                           \
    }

    // prologue
    WLOAD(0)
    ZSTAGE(0, 0)
    asm volatile("s_waitcnt vmcnt(4)" ::: "memory");   // W(0) regs done, Z(0) in flight
    WWRITE(0)
    asm volatile("s_waitcnt vmcnt(0)" ::: "memory");   // Z(0) landed
    __syncthreads();

    for (int sub = 0; sub < 24; ++sub) {
        const int cur = sub & 1, nxt = cur ^ 1;
        if (sub + 1 < 24) {
            WLOAD(sub + 1)         // 8 vmem, in flight across whole compute
            ZSTAGE(nxt, sub + 1)   // 4 vmem
        }
        // ---- compute: pure LDS (lgkm domain), no vmem waits ----
#pragma unroll
        for (int kfo = 0; kfo < 4; ++kfo) {
            bf16x8 wf = *reinterpret_cast<const bf16x8*>(
                wrow + (cur * 16 + lr) * 272 + kfo * 64 + (ln >> 4) * 16);
#pragma unroll
            for (int rt = 0; rt < 4; ++rt) {
                bf16x8 z = *reinterpret_cast<const bf16x8*>(&Zlds[cur][rt * 4 + kfo][ln][0]);
                acc[rt] = __builtin_amdgcn_mfma_f32_16x16x32_bf16(z, wf, acc[rt], 0, 0, 0);
            }
        }
        if (sub + 1 < 24) {
            asm volatile("s_waitcnt vmcnt(4)" ::: "memory");   // W(sub+1) done; Z(sub+1) still out
            __builtin_amdgcn_sched_barrier(0);
            WWRITE(nxt)
            asm volatile("s_waitcnt vmcnt(0)" ::: "memory");   // Z(sub+1) landed (issued ~3K cyc ago)
        }
        __syncthreads();   // Zlds[nxt] visible to all waves; Wbuf ds ordering anchored
    }
#undef WLOAD
#undef WWRITE
#undef ZSTAGE

    const int ocol = o0 + wv * 16 + lr;
#pragma unroll
    for (int rt = 0; rt < 4; ++rt)
#pragma unroll
        for (int r = 0; r < 4; ++r)
            part[((size_t)ksp * 64 + rt * 16 + rbase + r) * 4096 + ocol] = acc[rt][r];
}

// ---------------- Kernel 4: reduce 16 split-K partials + bias ----------------
__global__ __launch_bounds__(256) void k_reduce(const float* __restrict__ part,
                                                const float* __restrict__ bias,
                                                float* __restrict__ y) {
    const int idx = blockIdx.x * 256 + threadIdx.x;
    const int o = idx & 4095;
    const int b = idx >> 12;
    float s = bias[o];
#pragma unroll
    for (int ksp = 0; ksp < 16; ++ksp)
        s += part[((size_t)ksp * 64 + b) * 4096 + o];
    y[idx] = s;
}

extern "C" void kernel_launch(void* const* d_in, const int* in_sizes, int n_in,
                              void* d_out, int out_size, void* d_ws, size_t ws_size,
                              hipStream_t stream) {
    const float* x  = (const float*)d_in[0];
    const float* Wp = (const float*)d_in[1];
    const float* Wl = (const float*)d_in[2];
    const float* bl = (const float*)d_in[3];
    float* out = (float*)d_out;

    unsigned short* qkvb = (unsigned short*)d_ws;                       // 9437184 u16
    unsigned short* Zh   = (unsigned short*)((char*)d_ws + 18874368);   // 3145728 u16
    float*          part = (float*)((char*)d_ws + 25165824);            // 16x64x4096 f32
    float* y    = out;
    float* msk  = out + 262144;

    hipLaunchKernelGGL(k_qkv,    dim3(576),  dim3(256), 0, stream, x, Wp, qkvb);
    hipLaunchKernelGGL(k_attn,   dim3(768),  dim3(256), 0, stream, qkvb, msk, Zh);
    hipLaunchKernelGGL(k_lin,    dim3(1024), dim3(256), 0, stream, Zh, Wl, part);
    hipLaunchKernelGGL(k_reduce, dim3(1024), dim3(256), 0, stream, part, bl, y);
}

// Round 13
// 278.944 us; speedup vs baseline: 1.3598x; 1.0734x over previous
//
#include <hip/hip_runtime.h>
#include <math.h>

// B=64, S=64, H_DIM=768, N_HEADS=12, D=64. All I/O f32.
// 4 kernels. ws bytes: qkvb u16[9437184] @0 ; Zh u16[3145728] @18874368 ;
//           part f32[8][64][4096] @25165824
// d_out f32: y [262144] then masked_scores [3145728].
// Masked positions: ref=-inf -> finite NEG_BIG (never materialize inf:
// finite-math folds ==-INFINITY; expf(NEG_BIG-m)==0).
// All GEMMs plain bf16 MFMA, f32 accum.
// mfma_f32_16x16x32_bf16: A row=ln&15,k=(ln>>4)*8+j; B col=ln&15;
// C/D col=ln&15,row=(ln>>4)*4+reg.
// Z frag order: z_flat[b][k] at ((rt*1536+kf)*64+lz)*8+j, rt=b>>4, kf=k>>5,
// lz=((k>>3)&3)*16+(b&15), j=k&7 -> contiguous 1KB wave reads/stages.
// k_lin v8: single-round grid (512 = 8 kgroups x 64 units, 2 blocks/CU, no
// second dispatch round) + TRUE depth-2 W register pipeline: W(s+2) issued at
// top of sub s, waited end of sub s+1 (~2 subs >> 900cyc HBM latency) via
// counted vmcnt(8); Z staged 1 sub ahead via gload_lds (L2-hot, short
// latency). Compute phase touches only LDS.

#define NEG_BIG (-1.0e30f)

typedef __attribute__((ext_vector_type(8))) short bf16x8;
typedef __attribute__((ext_vector_type(4))) float f32x4;
typedef const __attribute__((address_space(1))) void gvoid_t;
typedef __attribute__((address_space(3))) void svoid_t;

static __device__ __forceinline__ unsigned short f2bf(float x) {
    unsigned u = __builtin_bit_cast(unsigned, x);
    return (unsigned short)((u + 0x7FFFu + ((u >> 16) & 1u)) >> 16);   // RNE
}
static __device__ __forceinline__ ushort4 f2bf4(float4 v) {
    ushort4 r; r.x = f2bf(v.x); r.y = f2bf(v.y); r.z = f2bf(v.z); r.w = f2bf(v.w); return r;
}

// ---------------- Kernel 1: QKV GEMM, plain bf16 MFMA ----------------
__global__ __launch_bounds__(256, 4) void k_qkv(const float* __restrict__ X,
                                                const float* __restrict__ Wp,
                                                unsigned short* __restrict__ qkvb) {
    __shared__ unsigned short Ah[128][72];
    __shared__ unsigned short Bh[128][72];
    const int t  = threadIdx.x;
    const int wv = t >> 6, ln = t & 63;
    const int lr = ln & 15;
    const int kq = (ln >> 4) * 8;
    const int rbase = (ln >> 4) * 4;
    const int m0 = (blockIdx.x / 18) * 128;
    const int j0 = (blockIdx.x % 18) * 128;
    const f32x4 zero4 = {0.f, 0.f, 0.f, 0.f};

    f32x4 acc[2][8];
#pragma unroll
    for (int rt = 0; rt < 2; ++rt)
#pragma unroll
        for (int ct = 0; ct < 8; ++ct) acc[rt][ct] = zero4;

    for (int k0 = 0; k0 < 768; k0 += 64) {
#pragma unroll
        for (int i = 0; i < 8; ++i) {
            const int q   = t + 256 * i;
            const int row = q >> 4;
            const int kc  = (q & 15) * 4;
            float4 xa = *reinterpret_cast<const float4*>(&X[(size_t)(m0 + row) * 768 + k0 + kc]);
            *reinterpret_cast<ushort4*>(&Ah[row][kc]) = f2bf4(xa);
            float4 wb = *reinterpret_cast<const float4*>(&Wp[(size_t)(j0 + row) * 768 + k0 + kc]);
            *reinterpret_cast<ushort4*>(&Bh[row][kc]) = f2bf4(wb);
        }
        __syncthreads();
#pragma unroll
        for (int ks = 0; ks < 2; ++ks) {
            const int kb = ks * 32 + kq;
            bf16x8 a0 = *reinterpret_cast<const bf16x8*>(&Ah[wv * 32 + lr][kb]);
            bf16x8 a1 = *reinterpret_cast<const bf16x8*>(&Ah[wv * 32 + 16 + lr][kb]);
#pragma unroll
            for (int ct = 0; ct < 8; ++ct) {
                bf16x8 bh = *reinterpret_cast<const bf16x8*>(&Bh[ct * 16 + lr][kb]);
                acc[0][ct] = __builtin_amdgcn_mfma_f32_16x16x32_bf16(a0, bh, acc[0][ct], 0, 0, 0);
                acc[1][ct] = __builtin_amdgcn_mfma_f32_16x16x32_bf16(a1, bh, acc[1][ct], 0, 0, 0);
            }
        }
        __syncthreads();
    }
#pragma unroll
    for (int rt = 0; rt < 2; ++rt)
#pragma unroll
        for (int ct = 0; ct < 8; ++ct)
#pragma unroll
            for (int r = 0; r < 4; ++r) {
                const int m = m0 + wv * 32 + rt * 16 + rbase + r;
                const int j = j0 + ct * 16 + lr;
                const int b = m >> 6, s = m & 63;
                const int n = j / 192, f = j % 192;
                qkvb[(((size_t)b * 12 + n) * 64 + s) * 192 + f] = f2bf(acc[rt][ct][r]);
            }
}

// ---------------- Kernel 2: attention per (b,n), plain bf16 MFMA ----------------
__global__ __launch_bounds__(256, 4) void k_attn(const unsigned short* __restrict__ qkvb,
                                                 float* __restrict__ msk,
                                                 unsigned short* __restrict__ Zh) {
    __shared__ unsigned short Qh[64][72];
    __shared__ unsigned short Kh[64][72];
    __shared__ unsigned short Vth[64][72];   // V transposed [d][s]
    __shared__ unsigned short Ph[64][72];
    const int t  = threadIdx.x;
    const int wv = t >> 6, ln = t & 63;
    const int lr = ln & 15;
    const int kq = (ln >> 4) * 8;
    const int rbase = (ln >> 4) * 4;
    const int bn = blockIdx.x;
    const int bb = bn / 12, nn = bn % 12;
    const unsigned short* base = qkvb + (size_t)bn * 12288;
    const f32x4 zero4 = {0.f, 0.f, 0.f, 0.f};

#pragma unroll
    for (int i = 0; i < 6; ++i) {
        const int q   = t + 256 * i;
        const int row = q / 24;
        const int c8  = (q % 24) * 8;
        const int sec = c8 >> 6;
        const int d0  = c8 & 63;
        bf16x8 v = *reinterpret_cast<const bf16x8*>(&base[(size_t)row * 192 + c8]);
        if (sec == 0) {
            *reinterpret_cast<bf16x8*>(&Qh[row][d0]) = v;
        } else if (sec == 1) {
            *reinterpret_cast<bf16x8*>(&Kh[row][d0]) = v;
        } else {
#pragma unroll
            for (int jj = 0; jj < 8; ++jj) Vth[d0 + jj][row] = (unsigned short)v[jj];
        }
    }
    __syncthreads();

    f32x4 acc[4];
#pragma unroll
    for (int ct = 0; ct < 4; ++ct) acc[ct] = zero4;
#pragma unroll
    for (int ks = 0; ks < 2; ++ks) {
        const int kb = ks * 32 + kq;
        bf16x8 qh = *reinterpret_cast<const bf16x8*>(&Qh[wv * 16 + lr][kb]);
#pragma unroll
        for (int ct = 0; ct < 4; ++ct) {
            bf16x8 kh = *reinterpret_cast<const bf16x8*>(&Kh[ct * 16 + lr][kb]);
            acc[ct] = __builtin_amdgcn_mfma_f32_16x16x32_bf16(qh, kh, acc[ct], 0, 0, 0);
        }
    }

    float s_[4][4];
#pragma unroll
    for (int ct = 0; ct < 4; ++ct)
#pragma unroll
        for (int r = 0; r < 4; ++r) {
            const int row = wv * 16 + rbase + r;
            const int col = ct * 16 + lr;
            float s = (col > row) ? NEG_BIG : acc[ct][r] * 0.125f;
            s_[ct][r] = s;
            msk[(size_t)bn * 4096 + (size_t)row * 64 + col] = s;
        }
    float m[4], sum[4], p[4][4];
#pragma unroll
    for (int r = 0; r < 4; ++r)
        m[r] = fmaxf(fmaxf(s_[0][r], s_[1][r]), fmaxf(s_[2][r], s_[3][r]));
#pragma unroll
    for (int off = 1; off <= 8; off <<= 1)
#pragma unroll
        for (int r = 0; r < 4; ++r) m[r] = fmaxf(m[r], __shfl_xor(m[r], off));
#pragma unroll
    for (int r = 0; r < 4; ++r) sum[r] = 0.f;
#pragma unroll
    for (int ct = 0; ct < 4; ++ct)
#pragma unroll
        for (int r = 0; r < 4; ++r) { p[ct][r] = expf(s_[ct][r] - m[r]); sum[r] += p[ct][r]; }
#pragma unroll
    for (int off = 1; off <= 8; off <<= 1)
#pragma unroll
        for (int r = 0; r < 4; ++r) sum[r] += __shfl_xor(sum[r], off);
#pragma unroll
    for (int ct = 0; ct < 4; ++ct)
#pragma unroll
        for (int r = 0; r < 4; ++r)
            Ph[wv * 16 + rbase + r][ct * 16 + lr] = f2bf(p[ct][r] * (1.f / sum[r]));
    // wave-local LDS dependency only

    f32x4 o_[4];
#pragma unroll
    for (int ct = 0; ct < 4; ++ct) o_[ct] = zero4;
#pragma unroll
    for (int ks = 0; ks < 2; ++ks) {
        const int kb = ks * 32 + kq;
        bf16x8 ph = *reinterpret_cast<const bf16x8*>(&Ph[wv * 16 + lr][kb]);
#pragma unroll
        for (int ct = 0; ct < 4; ++ct) {
            bf16x8 vh = *reinterpret_cast<const bf16x8*>(&Vth[ct * 16 + lr][kb]);
            o_[ct] = __builtin_amdgcn_mfma_f32_16x16x32_bf16(ph, vh, o_[ct], 0, 0, 0);
        }
    }
    const int rt_z = bb >> 4;
#pragma unroll
    for (int ct = 0; ct < 4; ++ct)
#pragma unroll
        for (int r = 0; r < 4; ++r) {
            const int srow = wv * 16 + rbase + r;
            const int d    = ct * 16 + lr;
            const int k    = nn * 4096 + srow * 64 + d;
            const int lz   = (((k >> 3) & 3) << 4) + (bb & 15);
            const size_t zi = (((size_t)rt_z * 1536 + (k >> 5)) * 64 + lz) * 8 + (k & 7);
            Zh[zi] = f2bf(o_[ct][r]);
        }
}

// ---------------- Kernel 3: output projection v8 ----------------
// part[kg][b][o] = sum_{k in 6144-chunk} Z[b][k] W[o][k]
// grid 512 = 8 kgroups x 64 units (kgroup = bid&7 -> one kgroup per XCD if
// round-robin dispatch; Z slice 786KB stays L2-hot). 48 subs of BK=128.
__global__ __launch_bounds__(256, 2) void k_lin(const unsigned short* __restrict__ Zh,
                                                const float* __restrict__ Wl,
                                                float* __restrict__ part) {
    __shared__ __align__(16) unsigned short Zlds[2][16][64][8];   // 32 KB [buf][rt*4+kfo][lane][8]
    __shared__ __align__(16) unsigned short Wbuf[4][2][16][136];  // 34.8 KB padded rows (272B)
    const int t  = threadIdx.x;
    const int wv = t >> 6, ln = t & 63;
    const int lr = ln & 15;
    const int rbase = (ln >> 4) * 4;
    const int kg   = blockIdx.x & 7;           // 0..7
    const int unit = blockIdx.x >> 3;          // 0..63
    const int o0   = unit * 64;
    const f32x4 zero4 = {0.f, 0.f, 0.f, 0.f};

    const int rlo = (ln >= 32) ? 1 : 0;
    const float* wbase = Wl + (size_t)(o0 + wv * 16) * 49152 + kg * 6144 + (ln & 31) * 4;
    char* wrow = (char*)&Wbuf[wv][0][0][0];

    f32x4 acc[4];
#pragma unroll
    for (int rt = 0; rt < 4; ++rt) acc[rt] = zero4;

    float4 wregA[8], wregB[8];
    // W load: instr i covers rows 2i (lanes 0-31) / 2i+1 (lanes 32-63);
    // lane 16B at (ln&31)*16 within the row's 512B sub-slice.
#define WLOAD(REG, sub_)                                                            \
    {                                                                               \
        _Pragma("unroll")                                                           \
        for (int i = 0; i < 8; ++i)                                                 \
            REG[i] = *reinterpret_cast<const float4*>(                              \
                wbase + (size_t)(2 * i + rlo) * 49152 + (sub_) * 128);              \
    }
#define WWRITE(buf_, REG)                                                           \
    {                                                                               \
        _Pragma("unroll")                                                           \
        for (int i = 0; i < 8; ++i) {                                               \
            unsigned u0 = (unsigned)f2bf(REG[i].x) | ((unsigned)f2bf(REG[i].y) << 16); \
            unsigned u1 = (unsigned)f2bf(REG[i].z) | ((unsigned)f2bf(REG[i].w) << 16); \
            uint2 pk; pk.x = u0; pk.y = u1;                                         \
            *reinterpret_cast<uint2*>(wrow + ((buf_) * 16 + 2 * i + rlo) * 272 + (ln & 31) * 8) = pk; \
        }                                                                           \
    }
    // Z stage: wave wv stages rt=wv, 4 x 1KB contiguous gload_lds
#define ZSTAGE(buf_, sub_)                                                          \
    {                                                                               \
        const int kf0 = kg * 192 + (sub_) * 4;                                      \
        _Pragma("unroll")                                                           \
        for (int q = 0; q < 4; ++q) {                                               \
            const unsigned short* src = Zh +                                        \
                ((size_t)(wv * 1536 + kf0 + q) * 64 + ln) * 8;                      \
            __builtin_amdgcn_global_load_lds((gvoid_t*)src,                         \
                (svoid_t*)&Zlds[buf_][wv * 4 + q][0][0], 16, 0, 0);                 \
        }                                                                           \
    }
#define COMPUTE(buf_)                                                               \
    {                                                                               \
        _Pragma("unroll")                                                           \
        for (int kfo = 0; kfo < 4; ++kfo) {                                         \
            bf16x8 wf = *reinterpret_cast<const bf16x8*>(                           \
                wrow + ((buf_) * 16 + lr) * 272 + kfo * 64 + (ln >> 4) * 16);       \
            _Pragma("unroll")                                                       \
            for (int rt = 0; rt < 4; ++rt) {                                        \
                bf16x8 z = *reinterpret_cast<const bf16x8*>(&Zlds[buf_][rt * 4 + kfo][ln][0]); \
                acc[rt] = __builtin_amdgcn_mfma_f32_16x16x32_bf16(z, wf, acc[rt], 0, 0, 0); \
            }                                                                       \
        }                                                                           \
    }

    // ---- prologue ----
    ZSTAGE(0, 0)
    WLOAD(wregA, 0)
    asm volatile("s_waitcnt vmcnt(0)" ::: "memory");
    WWRITE(0, wregA)
    WLOAD(wregB, 1)                      // W(1) in flight across sub 0
    __syncthreads();                     // Zlds[0] visible

    // ---- main loop: subs 0..45, invariant at top of even sub s:
    // outstanding (oldest first) = W(s+1) in bank for (s+1)&1 ----
    for (int sp = 0; sp < 23; ++sp) {
        const int s0 = sp * 2;           // even sub: compute buf0, WLOAD->A, WWRITE B
        // sub s0
        ZSTAGE(1, s0 + 1)
        WLOAD(wregA, s0 + 2)
        COMPUTE(0)
        asm volatile("s_waitcnt vmcnt(8)" ::: "memory");   // W(s0+1)+Z(s0+1) done; W(s0+2) out
        WWRITE(1, wregB)
        __syncthreads();
        // sub s0+1 (odd): compute buf1, WLOAD->B, WWRITE A
        ZSTAGE(0, s0 + 2)
        WLOAD(wregB, s0 + 3)
        COMPUTE(1)
        asm volatile("s_waitcnt vmcnt(8)" ::: "memory");
        WWRITE(0, wregA)
        __syncthreads();
    }
    // ---- tail: subs 46 (even), 47 (odd); W(47) already in flight in wregB ----
    ZSTAGE(1, 47)
    COMPUTE(0)
    asm volatile("s_waitcnt vmcnt(0)" ::: "memory");
    WWRITE(1, wregB)
    __syncthreads();
    COMPUTE(1)
#undef WLOAD
#undef WWRITE
#undef ZSTAGE
#undef COMPUTE

    const int ocol = o0 + wv * 16 + lr;
#pragma unroll
    for (int rt = 0; rt < 4; ++rt)
#pragma unroll
        for (int r = 0; r < 4; ++r)
            part[((size_t)kg * 64 + rt * 16 + rbase + r) * 4096 + ocol] = acc[rt][r];
}

// ---------------- Kernel 4: reduce 8 split-K partials + bias ----------------
__global__ __launch_bounds__(256) void k_reduce(const float* __restrict__ part,
                                                const float* __restrict__ bias,
                                                float* __restrict__ y) {
    const int idx = blockIdx.x * 256 + threadIdx.x;
    const int o = idx & 4095;
    const int b = idx >> 12;
    float s = bias[o];
#pragma unroll
    for (int kg = 0; kg < 8; ++kg)
        s += part[((size_t)kg * 64 + b) * 4096 + o];
    y[idx] = s;
}

extern "C" void kernel_launch(void* const* d_in, const int* in_sizes, int n_in,
                              void* d_out, int out_size, void* d_ws, size_t ws_size,
                              hipStream_t stream) {
    const float* x  = (const float*)d_in[0];
    const float* Wp = (const float*)d_in[1];
    const float* Wl = (const float*)d_in[2];
    const float* bl = (const float*)d_in[3];
    float* out = (float*)d_out;

    unsigned short* qkvb = (unsigned short*)d_ws;                       // 9437184 u16
    unsigned short* Zh   = (unsigned short*)((char*)d_ws + 18874368);   // 3145728 u16
    float*          part = (float*)((char*)d_ws + 25165824);            // 8x64x4096 f32
    float* y    = out;
    float* msk  = out + 262144;

    hipLaunchKernelGGL(k_qkv,    dim3(576),  dim3(256), 0, stream, x, Wp, qkvb);
    hipLaunchKernelGGL(k_attn,   dim3(768),  dim3(256), 0, stream, qkvb, msk, Zh);
    hipLaunchKernelGGL(k_lin,    dim3(512),  dim3(256), 0, stream, Zh, Wl, part);
    hipLaunchKernelGGL(k_reduce, dim3(1024), dim3(256), 0, stream, part, bl, y);
}